// Round 12
// baseline (139.368 us; speedup 1.0000x reference)
//
#include <hip/hip_runtime.h>
#include <math.h>

#define N_NODES 50000
#define N_EDGES 800000
#define D 128
#define NBKT 392            // buckets of 128 dst nodes: 392*128 = 50176 >= 50000
#define CHUNK 4096          // edges per partition block
#define NCHUNK ((N_EDGES + CHUNK - 1) / CHUNK)   // 196
#define CAPB 4096           // partition slot capacity per bucket
#define GEMM_BLOCKS ((N_NODES + 63) / 64)        // 782

typedef short bf16x8 __attribute__((ext_vector_type(8)));
typedef float f32x4 __attribute__((ext_vector_type(4)));

static __device__ __forceinline__ unsigned short f2bf_rn(float f) {
    unsigned u = __float_as_uint(f);
    unsigned r = (u + 0x7FFF + ((u >> 16) & 1)) >> 16;
    return (unsigned short)r;
}
static __device__ __forceinline__ float bf2f(unsigned short h) {
    return __uint_as_float(((unsigned)h) << 16);
}

// ---------------- setup: W hi-fragments (blocks 0-7) + gcur/row_start init (block 8) ----
// W fragment for mfma_f32_16x16x32_bf16 B operand: lane l of frag (kstep, ctile) holds
// B[k = kstep*32 + (l>>4)*8 + e][c = ctile*16 + (l&15)], e = 0..7.

__global__ __launch_bounds__(256) void setup(const float* __restrict__ W,
                                             unsigned short* __restrict__ wH,
                                             int* __restrict__ gcur,
                                             int* __restrict__ row_start) {
    if (blockIdx.x < 8) {
        int tid = blockIdx.x * 256 + threadIdx.x;   // 0..2047
        int kstep = tid >> 9;
        int ct = (tid >> 6) & 7;
        int lane = tid & 63;
        int kbase = kstep * 32 + ((lane >> 4) << 3);
        int c = ct * 16 + (lane & 15);
        #pragma unroll
        for (int e = 0; e < 8; ++e) {
            wH[tid * 8 + e] = f2bf_rn(W[(kbase + e) * 128 + c]);
        }
    } else {
        for (int j = threadIdx.x; j < NBKT; j += 256) gcur[j] = j * CAPB;
        if (threadIdx.x == 0) row_start[N_NODES] = N_EDGES;
    }
}

// ---------------- fat kernel: partition (blocks 0..195) || gemm (blocks 196..977) --------
// partition: register-staged 1-pass — per-thread <=16 edges in regs, ONE LDS-atomic
//   hist pass (the returned value IS the within-chunk bucket rank), one global
//   reserve atomic per bucket, then direct write part[goff[bk] + rank].
// gemm: h = (xh + xl) * wh via bf16x2 split MFMA. Only ~3 KB LDS now -> better overlap.

__global__ __launch_bounds__(256) void part_gemm(const int* __restrict__ ei,
                                                 int* __restrict__ gcur,
                                                 unsigned int* __restrict__ part,
                                                 const float* __restrict__ x,
                                                 const unsigned short* __restrict__ wH,
                                                 unsigned short* __restrict__ h) {
    __shared__ int hist[NBKT];
    __shared__ int goff[NBKT];
    int t = threadIdx.x;

    if (blockIdx.x < NCHUNK) {
        // ---------------- partition body (1-pass, register-staged) ----------------
        int base = blockIdx.x * CHUNK;
        int n = N_EDGES - base; if (n > CHUNK) n = CHUNK;

        for (int j = t; j < NBKT; j += 256) hist[j] = 0;
        __syncthreads();

        unsigned eregs[16];
        int rregs[16];
        #pragma unroll
        for (int k = 0; k < 16; ++k) {
            int i = t + k * 256;
            if (i < n) {
                unsigned s = (unsigned)ei[base + i];
                unsigned d = (unsigned)ei[N_EDGES + base + i];
                unsigned e = s | (d << 16);
                eregs[k] = e;
                rregs[k] = atomicAdd(&hist[d >> 7], 1);
            }
        }
        __syncthreads();
        for (int j = t; j < NBKT; j += 256) {
            goff[j] = atomicAdd(&gcur[j], hist[j]);
        }
        __syncthreads();
        #pragma unroll
        for (int k = 0; k < 16; ++k) {
            int i = t + k * 256;
            if (i < n) {
                unsigned e = eregs[k];
                part[goff[e >> 23] + rregs[k]] = e;
            }
        }
    } else {
        // ---------------- gemm body: h = (xh + xl) * wh ----------------
        int gb = blockIdx.x - NCHUNK;
        int wave = t >> 6;
        int lane = t & 63;
        int rowbase = gb * 64 + wave * 16;

        f32x4 acc[8];
        #pragma unroll
        for (int ct = 0; ct < 8; ++ct) acc[ct] = (f32x4)(0.f);

        int arow = rowbase + (lane & 15);
        if (arow >= N_NODES) arow = N_NODES - 1;
        const float* xrow = x + (size_t)arow * 128 + ((lane >> 4) << 3);

        #pragma unroll
        for (int kstep = 0; kstep < 4; ++kstep) {
            float4 a0 = *(const float4*)(xrow + kstep * 32);
            float4 a1 = *(const float4*)(xrow + kstep * 32 + 4);
            float av[8] = {a0.x, a0.y, a0.z, a0.w, a1.x, a1.y, a1.z, a1.w};
            bf16x8 ah, al;
            #pragma unroll
            for (int e = 0; e < 8; ++e) {
                unsigned short hb = f2bf_rn(av[e]);
                float res = av[e] - bf2f(hb);
                ah[e] = (short)hb;
                al[e] = (short)f2bf_rn(res);
            }
            const bf16x8* bh = (const bf16x8*)(wH + (size_t)(kstep * 8) * 64 * 8 + lane * 8);
            #pragma unroll
            for (int ct = 0; ct < 8; ++ct) {
                bf16x8 bhv = bh[ct * 64];
                acc[ct] = __builtin_amdgcn_mfma_f32_16x16x32_bf16(ah, bhv, acc[ct], 0, 0, 0);
                acc[ct] = __builtin_amdgcn_mfma_f32_16x16x32_bf16(al, bhv, acc[ct], 0, 0, 0);
            }
        }

        int rbase = rowbase + ((lane >> 4) << 2);
        int col = lane & 15;
        #pragma unroll
        for (int ct = 0; ct < 8; ++ct) {
            #pragma unroll
            for (int i = 0; i < 4; ++i) {
                int row = rbase + i;
                if (row < N_NODES) h[(size_t)row * 128 + ct * 16 + col] = f2bf_rn(acc[ct][i]);
            }
        }
    }
}

// ---------------- per-bucket CSR build (self-computed prefix, LDS image) ----------------

__global__ __launch_bounds__(256) void csr_build(const unsigned int* __restrict__ part,
                                                 const int* __restrict__ gcur,
                                                 int* __restrict__ row_start,
                                                 float* __restrict__ dinv,
                                                 unsigned short* __restrict__ ssrc16) {
    __shared__ unsigned int ebuf[CAPB];        // 16 KB
    __shared__ unsigned short img[CAPB];       // 8 KB
    __shared__ int exf[NBKT];
    __shared__ int sm2[256];
    __shared__ int h128[128];
    __shared__ int loff[128];
    __shared__ int sm[128];
    int t = threadIdx.x;
    int b = blockIdx.x;

    int i0 = 2 * t, i1 = i0 + 1;
    int a = (i0 < NBKT) ? (gcur[i0] - i0 * CAPB) : 0;
    int b2 = (i1 < NBKT) ? (gcur[i1] - i1 * CAPB) : 0;
    int ps = a + b2;
    sm2[t] = ps; __syncthreads();
    for (int o = 1; o < 256; o <<= 1) {
        int ad = (t >= o) ? sm2[t - o] : 0;
        __syncthreads();
        sm2[t] += ad;
        __syncthreads();
    }
    int ex = sm2[t] - ps;
    if (i0 < NBKT) exf[i0] = ex;
    if (i1 < NBKT) exf[i1] = ex + a;
    for (int j = t; j < 128; j += 256) h128[j] = 0;
    __syncthreads();

    int cnt = gcur[b] - b * CAPB;
    int cb = exf[b];
    int gb = b * CAPB;
    int nbase = b * 128;

    for (int i = t; i < cnt; i += 256) {
        unsigned e = part[gb + i];
        ebuf[i] = e;
        atomicAdd(&h128[(e >> 16) & 127], 1);
    }
    __syncthreads();
    if (t < 128) sm[t] = h128[t];
    __syncthreads();
    for (int o = 1; o < 128; o <<= 1) {
        int ad = 0;
        if (t < 128 && t >= o) ad = sm[t - o];
        __syncthreads();
        if (t < 128) sm[t] += ad;
        __syncthreads();
    }
    if (t < 128) {
        int exl = sm[t] - h128[t];
        loff[t] = exl;
        int node = nbase + t;
        if (node < N_NODES) {
            row_start[node] = cb + exl;
            dinv[node] = rsqrtf((float)(h128[t] + 1));
        }
        h128[t] = 0;   // reuse as placement cursor
    }
    __syncthreads();
    for (int i = t; i < cnt; i += 256) {
        unsigned e = ebuf[i];
        int j = (e >> 16) & 127;
        int p = loff[j] + atomicAdd(&h128[j], 1);
        img[p] = (unsigned short)(e & 0xffffu);
    }
    __syncthreads();
    for (int i = t; i < cnt; i += 256) ssrc16[cb + i] = img[i];
}

// ---------------- gather-aggregate (wave per node, bf16 h, u16 CSR, unroll 8) ----------------

__global__ __launch_bounds__(256) void aggregate(const unsigned int* __restrict__ hu,
                                                 const int* __restrict__ row_start,
                                                 const unsigned short* __restrict__ ssrc16,
                                                 const float* __restrict__ dinv,
                                                 const float* __restrict__ bias,
                                                 float* __restrict__ out) {
    int node = blockIdx.x * 4 + (threadIdx.x >> 6);
    int lane = threadIdx.x & 63;
    if (node >= N_NODES) return;
    int s = row_start[node];
    int t = row_start[node + 1];
    float accx = 0.f, accy = 0.f;
    for (int base = s; base < t; base += 64) {
        int c = t - base;
        if (c > 64) c = 64;
        int li = base + (lane < c ? lane : c - 1);
        int idx = (int)ssrc16[li];
        float dv = dinv[idx];
        int j = 0;
        for (; j + 8 <= c; j += 8) {
            int ss[8]; float dd[8]; unsigned uu[8];
            #pragma unroll
            for (int k = 0; k < 8; ++k) {
                ss[k] = __shfl(idx, j + k);
                dd[k] = __shfl(dv, j + k);
            }
            #pragma unroll
            for (int k = 0; k < 8; ++k) uu[k] = hu[(size_t)ss[k] * 64 + lane];
            #pragma unroll
            for (int k = 0; k < 8; ++k) {
                accx += dd[k] * __uint_as_float(uu[k] << 16);
                accy += dd[k] * __uint_as_float(uu[k] & 0xffff0000u);
            }
        }
        for (; j < c; ++j) {
            int sj = __shfl(idx, j);
            float dj = __shfl(dv, j);
            unsigned u = hu[(size_t)sj * 64 + lane];
            accx += dj * __uint_as_float(u << 16);
            accy += dj * __uint_as_float(u & 0xffff0000u);
        }
    }
    float di = dinv[node];
    unsigned us = hu[(size_t)node * 64 + lane];
    float2 bv = *(const float2*)&bias[2 * lane];
    float2 o;
    o.x = di * accx + di * di * __uint_as_float(us << 16) + bv.x;
    o.y = di * accy + di * di * __uint_as_float(us & 0xffff0000u) + bv.y;
    *(float2*)&out[(size_t)node * 128 + 2 * lane] = o;
}

// ---------------- launch ----------------

extern "C" void kernel_launch(void* const* d_in, const int* in_sizes, int n_in,
                              void* d_out, int out_size, void* d_ws, size_t ws_size,
                              hipStream_t stream) {
    const float* x  = (const float*)d_in[0];
    const int*   ei = (const int*)d_in[1];
    const float* W  = (const float*)d_in[2];
    const float* b  = (const float*)d_in[3];
    float* out = (float*)d_out;

    char* ws = (char*)d_ws;
    // NOTE: part must NOT alias h — partition and gemm run concurrently in part_gemm.
    unsigned short* h      = (unsigned short*)(ws + 0);        // 12,800,000
    int*   row_start       = (int*)  (ws + 12800000);          //    200,004
    float* dinv            = (float*)(ws + 13000016);          //    200,000
    unsigned short* ssrc16 = (unsigned short*)(ws + 13200016); //  1,600,000
    int*   gcur            = (int*)  (ws + 14800016);          //      1,568
    unsigned short* wH     = (unsigned short*)(ws + 14801600); //     32,768
    unsigned int*   part   = (unsigned int*)  (ws + 14834368); //  6,422,528 (disjoint)

    hipLaunchKernelGGL(setup,     dim3(9),                    dim3(256), 0, stream, W, wH, gcur, row_start);
    hipLaunchKernelGGL(part_gemm, dim3(NCHUNK + GEMM_BLOCKS), dim3(256), 0, stream,
                       ei, gcur, part, x, wH, h);
    hipLaunchKernelGGL(csr_build, dim3(NBKT),                 dim3(256), 0, stream, part, gcur, row_start, dinv, ssrc16);
    hipLaunchKernelGGL(aggregate, dim3((N_NODES + 3) / 4),    dim3(256), 0, stream,
                       (const unsigned int*)h, row_start, ssrc16, dinv, b, out);
}

// Round 13
// 137.026 us; speedup vs baseline: 1.0171x; 1.0171x over previous
//
#include <hip/hip_runtime.h>
#include <math.h>

#define N_NODES 50000
#define N_EDGES 800000
#define D 128
#define NBKT 392            // buckets of 128 dst nodes: 392*128 = 50176 >= 50000
#define CHUNK 4096          // edges per partition block
#define NCHUNK ((N_EDGES + CHUNK - 1) / CHUNK)   // 196
#define CAPB 4096           // partition slot capacity per bucket
#define GEMM_BLOCKS ((N_NODES + 63) / 64)        // 782

typedef short bf16x8 __attribute__((ext_vector_type(8)));
typedef float f32x4 __attribute__((ext_vector_type(4)));

static __device__ __forceinline__ unsigned short f2bf_rn(float f) {
    unsigned u = __float_as_uint(f);
    unsigned r = (u + 0x7FFF + ((u >> 16) & 1)) >> 16;
    return (unsigned short)r;
}
static __device__ __forceinline__ float bf2f(unsigned short h) {
    return __uint_as_float(((unsigned)h) << 16);
}

// ---------------- setup: W hi-fragments (blocks 0-7) + gcur/row_start init (block 8) ----

__global__ __launch_bounds__(256) void setup(const float* __restrict__ W,
                                             unsigned short* __restrict__ wH,
                                             int* __restrict__ gcur,
                                             int* __restrict__ row_start) {
    if (blockIdx.x < 8) {
        int tid = blockIdx.x * 256 + threadIdx.x;   // 0..2047
        int kstep = tid >> 9;
        int ct = (tid >> 6) & 7;
        int lane = tid & 63;
        int kbase = kstep * 32 + ((lane >> 4) << 3);
        int c = ct * 16 + (lane & 15);
        #pragma unroll
        for (int e = 0; e < 8; ++e) {
            wH[tid * 8 + e] = f2bf_rn(W[(kbase + e) * 128 + c]);
        }
    } else {
        for (int j = threadIdx.x; j < NBKT; j += 256) gcur[j] = j * CAPB;
        if (threadIdx.x == 0) row_start[N_NODES] = N_EDGES;
    }
}

// ---------------- fat kernel: partition (blocks 0..195) || gemm (blocks 196..977) --------

__global__ __launch_bounds__(256) void part_gemm(const int* __restrict__ ei,
                                                 int* __restrict__ gcur,
                                                 unsigned int* __restrict__ part,
                                                 const float* __restrict__ x,
                                                 const unsigned short* __restrict__ wH,
                                                 unsigned short* __restrict__ h) {
    __shared__ int hist[NBKT];
    __shared__ int goff[NBKT];
    int t = threadIdx.x;

    if (blockIdx.x < NCHUNK) {
        // ---------------- partition body (1-pass, register-staged) ----------------
        int base = blockIdx.x * CHUNK;
        int n = N_EDGES - base; if (n > CHUNK) n = CHUNK;

        for (int j = t; j < NBKT; j += 256) hist[j] = 0;
        __syncthreads();

        unsigned eregs[16];
        int rregs[16];
        #pragma unroll
        for (int k = 0; k < 16; ++k) {
            int i = t + k * 256;
            if (i < n) {
                unsigned s = (unsigned)ei[base + i];
                unsigned d = (unsigned)ei[N_EDGES + base + i];
                unsigned e = s | (d << 16);
                eregs[k] = e;
                rregs[k] = atomicAdd(&hist[d >> 7], 1);
            }
        }
        __syncthreads();
        for (int j = t; j < NBKT; j += 256) {
            goff[j] = atomicAdd(&gcur[j], hist[j]);
        }
        __syncthreads();
        #pragma unroll
        for (int k = 0; k < 16; ++k) {
            int i = t + k * 256;
            if (i < n) {
                unsigned e = eregs[k];
                part[goff[e >> 23] + rregs[k]] = e;
            }
        }
    } else {
        // ---------------- gemm body: h = (xh + xl) * wh ----------------
        int gb = blockIdx.x - NCHUNK;
        int wave = t >> 6;
        int lane = t & 63;
        int rowbase = gb * 64 + wave * 16;

        f32x4 acc[8];
        #pragma unroll
        for (int ct = 0; ct < 8; ++ct) acc[ct] = (f32x4)(0.f);

        int arow = rowbase + (lane & 15);
        if (arow >= N_NODES) arow = N_NODES - 1;
        const float* xrow = x + (size_t)arow * 128 + ((lane >> 4) << 3);

        #pragma unroll
        for (int kstep = 0; kstep < 4; ++kstep) {
            float4 a0 = *(const float4*)(xrow + kstep * 32);
            float4 a1 = *(const float4*)(xrow + kstep * 32 + 4);
            float av[8] = {a0.x, a0.y, a0.z, a0.w, a1.x, a1.y, a1.z, a1.w};
            bf16x8 ah, al;
            #pragma unroll
            for (int e = 0; e < 8; ++e) {
                unsigned short hb = f2bf_rn(av[e]);
                float res = av[e] - bf2f(hb);
                ah[e] = (short)hb;
                al[e] = (short)f2bf_rn(res);
            }
            const bf16x8* bh = (const bf16x8*)(wH + (size_t)(kstep * 8) * 64 * 8 + lane * 8);
            #pragma unroll
            for (int ct = 0; ct < 8; ++ct) {
                bf16x8 bhv = bh[ct * 64];
                acc[ct] = __builtin_amdgcn_mfma_f32_16x16x32_bf16(ah, bhv, acc[ct], 0, 0, 0);
                acc[ct] = __builtin_amdgcn_mfma_f32_16x16x32_bf16(al, bhv, acc[ct], 0, 0, 0);
            }
        }

        int rbase = rowbase + ((lane >> 4) << 2);
        int col = lane & 15;
        #pragma unroll
        for (int ct = 0; ct < 8; ++ct) {
            #pragma unroll
            for (int i = 0; i < 4; ++i) {
                int row = rbase + i;
                if (row < N_NODES) h[(size_t)row * 128 + ct * 16 + col] = f2bf_rn(acc[ct][i]);
            }
        }
    }
}

// ---------------- per-bucket CSR build (self-computed prefix, LDS image) ----------------

__global__ __launch_bounds__(256) void csr_build(const unsigned int* __restrict__ part,
                                                 const int* __restrict__ gcur,
                                                 int* __restrict__ row_start,
                                                 float* __restrict__ dinv,
                                                 unsigned short* __restrict__ ssrc16) {
    __shared__ unsigned int ebuf[CAPB];        // 16 KB
    __shared__ unsigned short img[CAPB];       // 8 KB
    __shared__ int exf[NBKT];
    __shared__ int sm2[256];
    __shared__ int h128[128];
    __shared__ int loff[128];
    __shared__ int sm[128];
    int t = threadIdx.x;
    int b = blockIdx.x;

    int i0 = 2 * t, i1 = i0 + 1;
    int a = (i0 < NBKT) ? (gcur[i0] - i0 * CAPB) : 0;
    int b2 = (i1 < NBKT) ? (gcur[i1] - i1 * CAPB) : 0;
    int ps = a + b2;
    sm2[t] = ps; __syncthreads();
    for (int o = 1; o < 256; o <<= 1) {
        int ad = (t >= o) ? sm2[t - o] : 0;
        __syncthreads();
        sm2[t] += ad;
        __syncthreads();
    }
    int ex = sm2[t] - ps;
    if (i0 < NBKT) exf[i0] = ex;
    if (i1 < NBKT) exf[i1] = ex + a;
    for (int j = t; j < 128; j += 256) h128[j] = 0;
    __syncthreads();

    int cnt = gcur[b] - b * CAPB;
    int cb = exf[b];
    int gb = b * CAPB;
    int nbase = b * 128;

    for (int i = t; i < cnt; i += 256) {
        unsigned e = part[gb + i];
        ebuf[i] = e;
        atomicAdd(&h128[(e >> 16) & 127], 1);
    }
    __syncthreads();
    if (t < 128) sm[t] = h128[t];
    __syncthreads();
    for (int o = 1; o < 128; o <<= 1) {
        int ad = 0;
        if (t < 128 && t >= o) ad = sm[t - o];
        __syncthreads();
        if (t < 128) sm[t] += ad;
        __syncthreads();
    }
    if (t < 128) {
        int exl = sm[t] - h128[t];
        loff[t] = exl;
        int node = nbase + t;
        if (node < N_NODES) {
            row_start[node] = cb + exl;
            dinv[node] = rsqrtf((float)(h128[t] + 1));
        }
        h128[t] = 0;   // reuse as placement cursor
    }
    __syncthreads();
    for (int i = t; i < cnt; i += 256) {
        unsigned e = ebuf[i];
        int j = (e >> 16) & 127;
        int p = loff[j] + atomicAdd(&h128[j], 1);
        img[p] = (unsigned short)(e & 0xffffu);
    }
    __syncthreads();
    for (int i = t; i < cnt; i += 256) ssrc16[cb + i] = img[i];
}

// ---------------- gather-aggregate v2: half-wave per edge, 2 rows per load instr ----------
// lanes 0-31 process even edges, lanes 32-63 odd edges; each lane covers 4 dims (uint2).
// One global_load_dwordx2 fetches TWO h-rows -> 2x rows in flight per instruction,
// half the shfl per edge. Cross-half combine via shfl_xor(32); lanes<32 write float4.

__global__ __launch_bounds__(256) void aggregate(const uint2* __restrict__ hu2,
                                                 const int* __restrict__ row_start,
                                                 const unsigned short* __restrict__ ssrc16,
                                                 const float* __restrict__ dinv,
                                                 const float* __restrict__ bias,
                                                 float* __restrict__ out) {
    int node = blockIdx.x * 4 + (threadIdx.x >> 6);
    int lane = threadIdx.x & 63;
    int half = lane >> 5;
    int sl = lane & 31;          // dims [4*sl, 4*sl+4)
    if (node >= N_NODES) return;
    int s = row_start[node];
    int t = row_start[node + 1];
    float a0 = 0.f, a1 = 0.f, a2 = 0.f, a3 = 0.f;
    for (int base = s; base < t; base += 64) {
        int c = t - base;
        if (c > 64) c = 64;
        int li = base + (lane < c ? lane : c - 1);
        int idx = (int)ssrc16[li];
        float dv = dinv[idx];
        int j = 0;
        for (; j + 16 <= c; j += 16) {          // 8 pairs = 16 edges per iter
            int rr[8]; float dd[8]; uint2 uu[8];
            #pragma unroll
            for (int k = 0; k < 8; ++k) {
                int src = j + 2 * k + half;
                rr[k] = __shfl(idx, src);
                dd[k] = __shfl(dv, src);
            }
            #pragma unroll
            for (int k = 0; k < 8; ++k) uu[k] = hu2[(size_t)rr[k] * 32 + sl];
            #pragma unroll
            for (int k = 0; k < 8; ++k) {
                a0 += dd[k] * __uint_as_float(uu[k].x << 16);
                a1 += dd[k] * __uint_as_float(uu[k].x & 0xffff0000u);
                a2 += dd[k] * __uint_as_float(uu[k].y << 16);
                a3 += dd[k] * __uint_as_float(uu[k].y & 0xffff0000u);
            }
        }
        for (; j + 2 <= c; j += 2) {            // leftover pairs
            int src = j + half;
            int r = __shfl(idx, src);
            float dj = __shfl(dv, src);
            uint2 u = hu2[(size_t)r * 32 + sl];
            a0 += dj * __uint_as_float(u.x << 16);
            a1 += dj * __uint_as_float(u.x & 0xffff0000u);
            a2 += dj * __uint_as_float(u.y << 16);
            a3 += dj * __uint_as_float(u.y & 0xffff0000u);
        }
        if (j < c) {                            // single leftover edge: half 0 only
            int r = __shfl(idx, j);
            float dj = __shfl(dv, j);
            if (half == 0) {
                uint2 u = hu2[(size_t)r * 32 + sl];
                a0 += dj * __uint_as_float(u.x << 16);
                a1 += dj * __uint_as_float(u.x & 0xffff0000u);
                a2 += dj * __uint_as_float(u.y << 16);
                a3 += dj * __uint_as_float(u.y & 0xffff0000u);
            }
        }
    }
    a0 += __shfl_xor(a0, 32);
    a1 += __shfl_xor(a1, 32);
    a2 += __shfl_xor(a2, 32);
    a3 += __shfl_xor(a3, 32);
    if (half == 0) {
        float di = dinv[node];
        uint2 us = hu2[(size_t)node * 32 + sl];
        float4 bv = *(const float4*)&bias[4 * sl];
        float4 o;
        o.x = di * a0 + di * di * __uint_as_float(us.x << 16) + bv.x;
        o.y = di * a1 + di * di * __uint_as_float(us.x & 0xffff0000u) + bv.y;
        o.z = di * a2 + di * di * __uint_as_float(us.y << 16) + bv.z;
        o.w = di * a3 + di * di * __uint_as_float(us.y & 0xffff0000u) + bv.w;
        *(float4*)&out[(size_t)node * 128 + 4 * sl] = o;
    }
}

// ---------------- launch ----------------

extern "C" void kernel_launch(void* const* d_in, const int* in_sizes, int n_in,
                              void* d_out, int out_size, void* d_ws, size_t ws_size,
                              hipStream_t stream) {
    const float* x  = (const float*)d_in[0];
    const int*   ei = (const int*)d_in[1];
    const float* W  = (const float*)d_in[2];
    const float* b  = (const float*)d_in[3];
    float* out = (float*)d_out;

    char* ws = (char*)d_ws;
    // NOTE: part must NOT alias h — partition and gemm run concurrently in part_gemm.
    unsigned short* h      = (unsigned short*)(ws + 0);        // 12,800,000
    int*   row_start       = (int*)  (ws + 12800000);          //    200,004
    float* dinv            = (float*)(ws + 13000016);          //    200,000
    unsigned short* ssrc16 = (unsigned short*)(ws + 13200016); //  1,600,000
    int*   gcur            = (int*)  (ws + 14800016);          //      1,568
    unsigned short* wH     = (unsigned short*)(ws + 14801600); //     32,768
    unsigned int*   part   = (unsigned int*)  (ws + 14834368); //  6,422,528 (disjoint)

    hipLaunchKernelGGL(setup,     dim3(9),                    dim3(256), 0, stream, W, wH, gcur, row_start);
    hipLaunchKernelGGL(part_gemm, dim3(NCHUNK + GEMM_BLOCKS), dim3(256), 0, stream,
                       ei, gcur, part, x, wH, h);
    hipLaunchKernelGGL(csr_build, dim3(NBKT),                 dim3(256), 0, stream, part, gcur, row_start, dinv, ssrc16);
    hipLaunchKernelGGL(aggregate, dim3((N_NODES + 3) / 4),    dim3(256), 0, stream,
                       (const uint2*)h, row_start, ssrc16, dinv, b, out);
}